// Round 2
// baseline (132.147 us; speedup 1.0000x reference)
//
#include <hip/hip_runtime.h>

#define BB  16
#define SS  2048
#define DD  64
#define OO  128

// ---------------------------------------------------------------------------
// Kernel 1: Y[b,o,d] = sum_t W[o,t] * X[b,t,d]   (rank-1-update tiled GEMM)
// grid = B(16) * t_splits(32) = 512 blocks, 256 threads, t-chunk = 64.
// LDS: W-chunk [128 o][64 t] 32KB (XOR-swizzled 16B chunks, key=(o>>3)&7),
//      X-chunk [64 t][64 d] 16KB linear.  Total 48KB -> 2-3 blocks/CU.
// Thread tile: 8(o) x 4(d); per 4-t step: 8+4 ds_read_b128 + 128 FMA
//   -> DS ~144 cyc vs VALU ~256 issue-cyc per wave: VALU-bound.
// Epilogue: 32 atomicAdd/thread into Y (memset'd beforehand).
// ---------------------------------------------------------------------------
__global__ __launch_bounds__(256, 2) void k_y(const float* __restrict__ X,
                                              const float* __restrict__ W,
                                              float* __restrict__ Y) {
    __shared__ float Wl[128 * 64];  // [o][t-chunk], swizzled
    __shared__ float Xl[64 * 64];   // [t][d], linear

    const int bx  = blockIdx.x;
    const int tsp = bx & 31;   // 0..31
    const int b   = bx >> 5;   // 0..15
    const int tid = threadIdx.x;
    const int t0  = tsp * 64;

    // stage X chunk: 64x64 floats, fully contiguous -> linear float4 copy
    const float* Xb = X + ((size_t)b * SS + t0) * DD;
#pragma unroll
    for (int i = 0; i < 4; ++i) {
        const int f = (tid + 256 * i) * 4;
        *(float4*)&Xl[f] = *(const float4*)(Xb + f);
    }
    // stage W chunk: rows 0..127, cols t0..t0+63, swizzle 16B chunks
#pragma unroll
    for (int i = 0; i < 8; ++i) {
        const int c   = tid + 256 * i;  // 0..2047
        const int row = c >> 4;         // o: 0..127
        const int tc  = c & 15;         // 16B chunk within row
        const float4 v = *(const float4*)(W + (size_t)row * SS + t0 + tc * 4);
        const int tcs = tc ^ ((row >> 3) & 7);
        *(float4*)&Wl[row * 64 + tcs * 4] = v;
    }
    __syncthreads();

    const int og  = tid & 15;   // o-group: o0 = og*8
    const int dg  = tid >> 4;   // d-group: d0 = dg*4
    const int o0  = og * 8;
    const int d0  = dg * 4;
    const int key = og & 7;     // == ((o0+j)>>3)&7 for j<8

    float acc[8][4];
#pragma unroll
    for (int j = 0; j < 8; ++j)
#pragma unroll
        for (int k = 0; k < 4; ++k) acc[j][k] = 0.f;

#pragma unroll 4
    for (int tc = 0; tc < 16; ++tc) {
        float4 wv[8], xv[4];
        const int tcs = (tc ^ key) << 2;
#pragma unroll
        for (int j = 0; j < 8; ++j)
            wv[j] = *(const float4*)&Wl[(o0 + j) * 64 + tcs];
#pragma unroll
        for (int i = 0; i < 4; ++i)
            xv[i] = *(const float4*)&Xl[(tc * 4 + i) * 64 + d0];
#pragma unroll
        for (int j = 0; j < 8; ++j) {
            const float* wp = (const float*)&wv[j];
#pragma unroll
            for (int i = 0; i < 4; ++i) {
                const float* xp = (const float*)&xv[i];
#pragma unroll
                for (int k = 0; k < 4; ++k)
                    acc[j][k] += wp[i] * xp[k];
            }
        }
    }

    float* Yb = Y + ((size_t)b * OO + o0) * DD + d0;
#pragma unroll
    for (int j = 0; j < 8; ++j)
#pragma unroll
        for (int k = 0; k < 4; ++k)
            atomicAdd(Yb + (size_t)j * DD + k, acc[j][k]);
}

// ---------------------------------------------------------------------------
// Kernel 2: out[b,s,o] = sum_d X[b,s,d] * Y[b,o,d] + bias[o]
// grid = B(16) * s_tiles(32) = 512 blocks, 256 threads.
// LDS: X tile 64x64 (16KB) + Y[b] 128x64 (32KB), XOR-swizzled 16B chunks so
// ds_read_b128 stays 16B-aligned with <=2-way bank aliasing (free on wave64).
// Each thread: 4(s) x 8(o) register tile, K=64 inner product.
// ---------------------------------------------------------------------------
__device__ __forceinline__ int swz(int row, int dc) {  // float index of chunk
    return row * 64 + (((dc ^ (row >> 3)) & 15) << 2);
}

__global__ __launch_bounds__(256) void k_out(const float* __restrict__ X,
                                             const float* __restrict__ Y,
                                             const float* __restrict__ bias,
                                             float* __restrict__ out) {
    __shared__ float Xl[64 * 64];
    __shared__ float Yl[128 * 64];

    const int bx  = blockIdx.x;
    const int b   = bx >> 5;
    const int s0  = (bx & 31) * 64;
    const int tid = threadIdx.x;

    const float* Xt = X + ((size_t)b * SS + s0) * DD;  // 4096 contiguous floats
    const float* Yb = Y + (size_t)b * OO * DD;         // 8192 contiguous floats

    // stage X tile (4 float4 / thread)
#pragma unroll
    for (int i = 0; i < 4; ++i) {
        const int f = (tid + 256 * i) * 4;
        const float4 v = *(const float4*)(Xt + f);
        const int s  = f >> 6;
        const int dc = (f >> 2) & 15;
        *(float4*)&Xl[swz(s, dc)] = v;
    }
    // stage Y[b] (8 float4 / thread)
#pragma unroll
    for (int i = 0; i < 8; ++i) {
        const int f = (tid + 256 * i) * 4;
        const float4 v = *(const float4*)(Yb + f);
        const int o  = f >> 6;
        const int dc = (f >> 2) & 15;
        *(float4*)&Yl[swz(o, dc)] = v;
    }

    const int to = tid & 15;   // o-tile 8 wide
    const int ts = tid >> 4;   // s-tile 4 wide

    const float4 bv0 = *(const float4*)(bias + to * 8);
    const float4 bv1 = *(const float4*)(bias + to * 8 + 4);

    float acc[4][8];
#pragma unroll
    for (int i = 0; i < 4; ++i) {
        acc[i][0] = bv0.x; acc[i][1] = bv0.y; acc[i][2] = bv0.z; acc[i][3] = bv0.w;
        acc[i][4] = bv1.x; acc[i][5] = bv1.y; acc[i][6] = bv1.z; acc[i][7] = bv1.w;
    }

    __syncthreads();

#pragma unroll 4
    for (int dc = 0; dc < 16; ++dc) {
        float4 xv[4], yv[8];
#pragma unroll
        for (int i = 0; i < 4; ++i)
            xv[i] = *(const float4*)&Xl[swz(ts * 4 + i, dc)];
#pragma unroll
        for (int j = 0; j < 8; ++j)
            yv[j] = *(const float4*)&Yl[swz(to * 8 + j, dc)];
#pragma unroll
        for (int i = 0; i < 4; ++i)
#pragma unroll
            for (int j = 0; j < 8; ++j) {
                acc[i][j] += xv[i].x * yv[j].x;
                acc[i][j] += xv[i].y * yv[j].y;
                acc[i][j] += xv[i].z * yv[j].z;
                acc[i][j] += xv[i].w * yv[j].w;
            }
    }

    float* op = out + ((size_t)b * SS + s0 + ts * 4) * OO + to * 8;
#pragma unroll
    for (int i = 0; i < 4; ++i) {
        *(float4*)(op + (size_t)i * OO)     = make_float4(acc[i][0], acc[i][1], acc[i][2], acc[i][3]);
        *(float4*)(op + (size_t)i * OO + 4) = make_float4(acc[i][4], acc[i][5], acc[i][6], acc[i][7]);
    }
}

extern "C" void kernel_launch(void* const* d_in, const int* in_sizes, int n_in,
                              void* d_out, int out_size, void* d_ws, size_t ws_size,
                              hipStream_t stream) {
    const float* X    = (const float*)d_in[0];  // [B,S,D]
    const float* W    = (const float*)d_in[1];  // [OUT,S]
    const float* bias = (const float*)d_in[2];  // [OUT]
    float* out = (float*)d_out;                 // [B,S,OUT]
    float* Y   = (float*)d_ws;                  // [B,OUT,D] = 512KB scratch

    hipMemsetAsync(d_ws, 0, (size_t)BB * OO * DD * sizeof(float), stream);
    k_y<<<dim3(512), dim3(256), 0, stream>>>(X, W, Y);
    k_out<<<dim3(512), dim3(256), 0, stream>>>(X, Y, bias, out);
}

// Round 3
// 95.842 us; speedup vs baseline: 1.3788x; 1.3788x over previous
//
#include <hip/hip_runtime.h>

#define BB 16
#define SS 2048
#define DD 64
#define OO 128
#define YN (BB * OO * DD)   // 131072 elements of Y

// ---------------------------------------------------------------------------
// k_y<SPLITS>: partial Y[b,o,d] = sum over this block's K-range of W[o,t]*X[b,t,d]
// grid = BB*SPLITS blocks, 512 threads (8 waves -> 2 blocks/CU -> 4 waves/SIMD).
// LDS: Wl [128 o][64 t] 32KB, XOR-swizzled 16B chunks key=(o>>2)&7 so the 32
//      broadcast rows of a compute read spread over all 8 bank-groups
//      (4 distinct chunks/group = optimal 4-phase LDS BW).
//      Xl [64 t][64 d] 16KB linear (reads are 2-chunk broadcast, conflict-free).
// Thread tile 4(o) x 4(d); per 16 tc-steps: 8 ds_read_b128 + 64 FMA each.
// NO atomics: plain float4 stores into a private slab Ypart[split][b][o][d].
// ---------------------------------------------------------------------------
template <int SPLITS>
__global__ __launch_bounds__(512, 4) void k_y(const float* __restrict__ X,
                                              const float* __restrict__ W,
                                              float* __restrict__ Yp) {
    __shared__ float Wl[128 * 64];
    __shared__ float Xl[64 * 64];

    const int bx  = blockIdx.x;
    const int p   = bx % SPLITS;
    const int b   = bx / SPLITS;
    const int tid = threadIdx.x;
    const int og  = tid & 31;  const int o0 = og * 4;
    const int dg  = tid >> 5;  const int d0 = dg * 4;   // dg 0..15
    const int key = og & 7;    // == ((o0+j)>>2)&7 for j<4

    float acc[4][4];
#pragma unroll
    for (int j = 0; j < 4; ++j)
#pragma unroll
        for (int k = 0; k < 4; ++k) acc[j][k] = 0.f;

    const int KCH = (SS / SPLITS) / 64;   // 64-wide t-chunks per block
    for (int ch = 0; ch < KCH; ++ch) {
        const int t0 = p * (SS / SPLITS) + ch * 64;

        // stage X chunk: 64t x 64d = 4096 contiguous floats, 2 float4/thread
        const float* Xb = X + ((size_t)b * SS + t0) * DD;
#pragma unroll
        for (int i = 0; i < 2; ++i) {
            const int f = (tid + 512 * i) * 4;
            *(float4*)&Xl[f] = *(const float4*)(Xb + f);
        }
        // stage W chunk: 128 rows x 16 chunks, 4 float4/thread, xor-swizzled
#pragma unroll
        for (int i = 0; i < 4; ++i) {
            const int c   = tid + 512 * i;   // 0..2047
            const int row = c >> 4;
            const int tc  = c & 15;
            const int col = tc ^ ((row >> 2) & 7);
            *(float4*)&Wl[row * 64 + col * 4] =
                *(const float4*)(W + (size_t)row * SS + t0 + tc * 4);
        }
        __syncthreads();

#pragma unroll
        for (int tc = 0; tc < 16; ++tc) {
            float4 wv[4], xv[4];
            const int wcol = ((tc ^ key) & 15) * 4;
#pragma unroll
            for (int j = 0; j < 4; ++j)
                wv[j] = *(const float4*)&Wl[(o0 + j) * 64 + wcol];
#pragma unroll
            for (int i = 0; i < 4; ++i)
                xv[i] = *(const float4*)&Xl[(tc * 4 + i) * 64 + d0];
#pragma unroll
            for (int j = 0; j < 4; ++j) {
                const float* wp = (const float*)&wv[j];
#pragma unroll
                for (int i = 0; i < 4; ++i) {
                    const float* xp = (const float*)&xv[i];
#pragma unroll
                    for (int k = 0; k < 4; ++k)
                        acc[j][k] += wp[i] * xp[k];
                }
            }
        }
        if (ch + 1 < KCH) __syncthreads();
    }

    float* o = Yp + (((size_t)p * BB + b) * OO + o0) * DD + d0;
#pragma unroll
    for (int j = 0; j < 4; ++j)
        *(float4*)(o + (size_t)j * DD) =
            make_float4(acc[j][0], acc[j][1], acc[j][2], acc[j][3]);
}

// ---------------------------------------------------------------------------
// k_red<SPLITS>: Y[n] = sum_p Ypart[p][n].  256 blocks x 128 thr, float4 each.
// ---------------------------------------------------------------------------
template <int SPLITS>
__global__ void k_red(const float* __restrict__ Yp, float* __restrict__ Y) {
    const int n = (blockIdx.x * 128 + threadIdx.x) * 4;
    float4 a = *(const float4*)(Yp + n);
#pragma unroll
    for (int p = 1; p < SPLITS; ++p) {
        const float4 v = *(const float4*)(Yp + (size_t)p * YN + n);
        a.x += v.x; a.y += v.y; a.z += v.z; a.w += v.w;
    }
    *(float4*)(Y + n) = a;
}

// ---------------------------------------------------------------------------
// k_out: out[b,s,o] = sum_d X[b,s,d]*Y[b,o,d] + bias[o]
// grid = 16b x 32 s-tiles = 512 blocks, 512 threads (4 waves/SIMD).
// LDS: Xl [64 s][68] padded stride (compute reads hit 4 distinct bank-groups,
//      conflict-free); Yl [128 o][64] xor key=(o>>3)&7 (2 rows/group = free).
// Thread tile 2(s) x 8(o); per dc-step: 10 ds_read_b128 + 64 FMA.
// ---------------------------------------------------------------------------
__global__ __launch_bounds__(512, 4) void k_out(const float* __restrict__ X,
                                                const float* __restrict__ Y,
                                                const float* __restrict__ bias,
                                                float* __restrict__ out) {
    __shared__ float Xl[64 * 68];
    __shared__ float Yl[128 * 64];

    const int bx  = blockIdx.x;
    const int b   = bx >> 5;
    const int s0  = (bx & 31) * 64;
    const int tid = threadIdx.x;
    const int to  = tid & 15;   // o0 = to*8
    const int ts  = tid >> 4;   // 0..31, s = s0 + ts*2 + {0,1}
    const int key = to & 7;     // == ((to*8+j)>>3)&7 for j<8

    // stage X tile: 64x64 floats, padded rows (stride 68)
    const float* Xt = X + ((size_t)b * SS + s0) * DD;
#pragma unroll
    for (int i = 0; i < 2; ++i) {
        const int c = tid + 512 * i;   // chunk 0..1023
        const int s = c >> 4, dc = c & 15;
        *(float4*)&Xl[s * 68 + dc * 4] = *(const float4*)(Xt + c * 4);
    }
    // stage Y[b]: 128x64 floats, xor-swizzled chunks
    const float* Yb = Y + (size_t)b * OO * DD;
#pragma unroll
    for (int i = 0; i < 4; ++i) {
        const int c = tid + 512 * i;   // chunk 0..2047
        const int o = c >> 4, dc = c & 15;
        const int col = dc ^ ((o >> 3) & 7);
        *(float4*)&Yl[o * 64 + col * 4] = *(const float4*)(Yb + c * 4);
    }

    const float4 bv0 = *(const float4*)(bias + to * 8);
    const float4 bv1 = *(const float4*)(bias + to * 8 + 4);
    float acc[2][8];
#pragma unroll
    for (int i = 0; i < 2; ++i) {
        acc[i][0] = bv0.x; acc[i][1] = bv0.y; acc[i][2] = bv0.z; acc[i][3] = bv0.w;
        acc[i][4] = bv1.x; acc[i][5] = bv1.y; acc[i][6] = bv1.z; acc[i][7] = bv1.w;
    }
    __syncthreads();

#pragma unroll
    for (int dc = 0; dc < 16; ++dc) {
        float4 xv[2], yv[8];
#pragma unroll
        for (int i = 0; i < 2; ++i)
            xv[i] = *(const float4*)&Xl[(ts * 2 + i) * 68 + dc * 4];
        const int ycol = ((dc ^ key) & 15) * 4;
#pragma unroll
        for (int j = 0; j < 8; ++j)
            yv[j] = *(const float4*)&Yl[(to * 8 + j) * 64 + ycol];
#pragma unroll
        for (int i = 0; i < 2; ++i) {
            const float* xp = (const float*)&xv[i];
#pragma unroll
            for (int j = 0; j < 8; ++j) {
                const float* yp = (const float*)&yv[j];
                acc[i][j] += xp[0] * yp[0];
                acc[i][j] += xp[1] * yp[1];
                acc[i][j] += xp[2] * yp[2];
                acc[i][j] += xp[3] * yp[3];
            }
        }
    }

#pragma unroll
    for (int i = 0; i < 2; ++i) {
        float* op = out + ((size_t)b * SS + s0 + ts * 2 + i) * OO + to * 8;
        *(float4*)op       = make_float4(acc[i][0], acc[i][1], acc[i][2], acc[i][3]);
        *(float4*)(op + 4) = make_float4(acc[i][4], acc[i][5], acc[i][6], acc[i][7]);
    }
}

extern "C" void kernel_launch(void* const* d_in, const int* in_sizes, int n_in,
                              void* d_out, int out_size, void* d_ws, size_t ws_size,
                              hipStream_t stream) {
    const float* X    = (const float*)d_in[0];  // [B,S,D]
    const float* W    = (const float*)d_in[1];  // [OUT,S]
    const float* bias = (const float*)d_in[2];  // [OUT]
    float* out = (float*)d_out;                 // [B,S,OUT]

    float* Y  = (float*)d_ws;                   // [B,OUT,D] 512KB
    float* Yp = (float*)d_ws + YN;              // [SPLITS,B,OUT,D]

    const size_t need32 = (size_t)(1 + 32) * YN * 4;  // ~17.3 MB
    const size_t need8  = (size_t)(1 + 8)  * YN * 4;  // ~4.7 MB
    const size_t need2  = (size_t)(1 + 2)  * YN * 4;  // ~1.6 MB

    if (ws_size >= need32) {
        k_y<32><<<dim3(BB * 32), dim3(512), 0, stream>>>(X, W, Yp);
        k_red<32><<<dim3(256), dim3(128), 0, stream>>>(Yp, Y);
    } else if (ws_size >= need8) {
        k_y<8><<<dim3(BB * 8), dim3(512), 0, stream>>>(X, W, Yp);
        k_red<8><<<dim3(256), dim3(128), 0, stream>>>(Yp, Y);
    } else if (ws_size >= need2) {
        k_y<2><<<dim3(BB * 2), dim3(512), 0, stream>>>(X, W, Yp);
        k_red<2><<<dim3(256), dim3(128), 0, stream>>>(Yp, Y);
    } else {
        // last resort: single split writes Y directly, no reduction needed
        k_y<1><<<dim3(BB), dim3(512), 0, stream>>>(X, W, Y);
    }
    k_out<<<dim3(512), dim3(512), 0, stream>>>(X, Y, bias, out);
}

// Round 4
// 93.922 us; speedup vs baseline: 1.4070x; 1.0204x over previous
//
#include <hip/hip_runtime.h>

#define BB 16
#define SS 2048
#define DD 64
#define OO 128
#define YN (BB * OO * DD)   // 131072 Y elements

typedef __attribute__((ext_vector_type(8))) short short8;   // 8 bf16 = 4 VGPRs
typedef __attribute__((ext_vector_type(4))) float f32x4;

__device__ __forceinline__ unsigned short f2bf(float f) {   // RNE fp32->bf16
    unsigned int u = __float_as_uint(f);
    return (unsigned short)((u + 0x7FFF + ((u >> 16) & 1)) >> 16);
}

// ---------------------------------------------------------------------------
// k_prep: XB[b][t][d] = bf16(X)        (row-major, d contiguous)
//         XT[b][d][t] = bf16(X) transposed (t contiguous)  — via LDS tile
//         WB[o][t]    = bf16(W)        (t contiguous)
// blocks 0..511: (b, 64-wide t-tile). blocks 512..575: W chunks.
// ---------------------------------------------------------------------------
__global__ __launch_bounds__(256) void k_prep(const float* __restrict__ X,
                                              const float* __restrict__ W,
                                              unsigned short* __restrict__ XB,
                                              unsigned short* __restrict__ XT,
                                              unsigned short* __restrict__ WB) {
    const int bx  = blockIdx.x;
    const int tid = threadIdx.x;
    if (bx < 512) {
        __shared__ unsigned short Xt[64 * 72];   // [d][t], stride 72 (16B-aligned rows)
        const int b  = bx >> 5;
        const int tt = bx & 31;
        const float*    Xs  = X  + ((size_t)b * SS + tt * 64) * DD;
        unsigned short* XBs = XB + ((size_t)b * SS + tt * 64) * DD;
#pragma unroll
        for (int i = 0; i < 4; ++i) {
            const int f = (tid + 256 * i) * 4;        // linear elem in 64x64 tile
            const float4 v = *(const float4*)(Xs + f);
            ushort4 h;
            h.x = f2bf(v.x); h.y = f2bf(v.y); h.z = f2bf(v.z); h.w = f2bf(v.w);
            *(ushort4*)(XBs + f) = h;
            const int tl = f >> 6;                    // t within tile
            const int d  = f & 63;                    // d (multiple of 4)
            Xt[(d + 0) * 72 + tl] = h.x;
            Xt[(d + 1) * 72 + tl] = h.y;
            Xt[(d + 2) * 72 + tl] = h.z;
            Xt[(d + 3) * 72 + tl] = h.w;
        }
        __syncthreads();
        const int d   = tid >> 2;
        const int seg = tid & 3;
        unsigned short*       o = XT + ((size_t)b * DD + d) * SS + tt * 64 + seg * 16;
        const unsigned short* r = &Xt[d * 72 + seg * 16];
        *(uint4*)(o)     = *(const uint4*)(r);        // 16B stores, aligned
        *(uint4*)(o + 8) = *(const uint4*)(r + 8);
    } else {
        const size_t base = (size_t)(bx - 512) * 4096;
#pragma unroll
        for (int i = 0; i < 4; ++i) {
            const size_t f = base + (size_t)(tid + 256 * i) * 4;
            const float4 v = *(const float4*)(W + f);
            ushort4 h;
            h.x = f2bf(v.x); h.y = f2bf(v.y); h.z = f2bf(v.z); h.w = f2bf(v.w);
            *(ushort4*)(WB + f) = h;
        }
    }
}

// ---------------------------------------------------------------------------
// k_y2<SPL>: partial Y[b,o,d] (fp32) = sum over K-slice of W[o,t]*X[t,d],
// bf16 MFMA 16x16x32, fragments loaded DIRECTLY from global (16B/lane, K
// contiguous in both WB[o][t] and XT[d][t]) — no LDS, high occupancy.
// grid = SPL*16 blocks (b = bx&15 so adjacent blocks share the W chunk in L2),
// 256 thr = 4 waves; wave w owns o-rows [w*32, w*32+32) x all 64 d.
// ---------------------------------------------------------------------------
template <int SPL>
__global__ __launch_bounds__(256) void k_y2(const unsigned short* __restrict__ WB,
                                            const unsigned short* __restrict__ XT,
                                            float* __restrict__ Yp) {
    const int bx  = blockIdx.x;
    const int b   = bx & 15;
    const int p   = bx >> 4;
    const int tid = threadIdx.x;
    const int w   = tid >> 6;
    const int l   = tid & 63;
    const int n   = l & 15;       // A-row / B-col lane index
    const int q   = l >> 4;       // quad: k-offset q*8
    const int t0  = p * (SS / SPL);

    f32x4 acc[2][4];
#pragma unroll
    for (int i = 0; i < 2; ++i)
#pragma unroll
        for (int j = 0; j < 4; ++j) acc[i][j] = {0.f, 0.f, 0.f, 0.f};

#pragma unroll
    for (int kk = 0; kk < SS / SPL; kk += 32) {
        const int tcol = t0 + kk + q * 8;
        short8 a[2], bf[4];
#pragma unroll
        for (int i = 0; i < 2; ++i)
            a[i] = *(const short8*)(WB + (size_t)(w * 32 + i * 16 + n) * SS + tcol);
#pragma unroll
        for (int j = 0; j < 4; ++j)
            bf[j] = *(const short8*)(XT + ((size_t)b * DD + j * 16 + n) * SS + tcol);
#pragma unroll
        for (int i = 0; i < 2; ++i)
#pragma unroll
            for (int j = 0; j < 4; ++j)
                acc[i][j] = __builtin_amdgcn_mfma_f32_16x16x32_bf16(a[i], bf[j], acc[i][j], 0, 0, 0);
    }

    float* Yb = Yp + ((size_t)p * BB + b) * OO * DD;
#pragma unroll
    for (int i = 0; i < 2; ++i) {
        const int orow = w * 32 + i * 16 + q * 4;     // D: row = q*4 + reg
#pragma unroll
        for (int j = 0; j < 4; ++j)
#pragma unroll
            for (int r = 0; r < 4; ++r)
                Yb[(size_t)(orow + r) * DD + j * 16 + n] = acc[i][j][r];
    }
}

// ---------------------------------------------------------------------------
// k_red<SPL>: YB[n] (bf16) = sum_p Yp[p][n].  128 blocks x 256 thr, float4.
// ---------------------------------------------------------------------------
template <int SPL>
__global__ __launch_bounds__(256) void k_red(const float* __restrict__ Yp,
                                             unsigned short* __restrict__ YB) {
    const size_t nidx = ((size_t)blockIdx.x * 256 + threadIdx.x) * 4;
    float4 a = *(const float4*)(Yp + nidx);
#pragma unroll
    for (int p = 1; p < SPL; ++p) {
        const float4 v = *(const float4*)(Yp + (size_t)p * YN + nidx);
        a.x += v.x; a.y += v.y; a.z += v.z; a.w += v.w;
    }
    ushort4 h;
    h.x = f2bf(a.x); h.y = f2bf(a.y); h.z = f2bf(a.z); h.w = f2bf(a.w);
    *(ushort4*)(YB + nidx) = h;
}

// ---------------------------------------------------------------------------
// k_out2: out[b,s,o] = sum_d XB[b,s,d]*YB[b,o,d] + bias[o], bf16 MFMA,
// frags direct from global (K=64 contiguous in both operands).
// grid = 16b x 32 s-tiles (b = bx>>5: adjacent blocks share YB[b] in L2),
// 256 thr; wave w owns s-rows [s0+w*16, +16) x all 128 o.
// Epilogue: D tiles -> LDS (stride 132, 2-way banks = free) -> coalesced
// 512B row stores with bias add.
// ---------------------------------------------------------------------------
__global__ __launch_bounds__(256) void k_out2(const unsigned short* __restrict__ XB,
                                              const unsigned short* __restrict__ YB,
                                              const float* __restrict__ bias,
                                              float* __restrict__ out) {
    __shared__ float Ol[64 * 132];
    const int bx  = blockIdx.x;
    const int b   = bx >> 5;
    const int s0  = (bx & 31) * 64;
    const int tid = threadIdx.x;
    const int w   = tid >> 6;
    const int l   = tid & 63;
    const int n   = l & 15;
    const int q   = l >> 4;

    f32x4 acc[8];
#pragma unroll
    for (int j = 0; j < 8; ++j) acc[j] = {0.f, 0.f, 0.f, 0.f};

    const unsigned short* Xs = XB + ((size_t)b * SS + s0 + w * 16 + n) * DD;
    const unsigned short* Ys = YB + (size_t)b * OO * DD;

#pragma unroll
    for (int kk = 0; kk < DD; kk += 32) {
        const short8 a = *(const short8*)(Xs + kk + q * 8);
#pragma unroll
        for (int j = 0; j < 8; ++j) {
            const short8 bf = *(const short8*)(Ys + (size_t)(j * 16 + n) * DD + kk + q * 8);
            acc[j] = __builtin_amdgcn_mfma_f32_16x16x32_bf16(a, bf, acc[j], 0, 0, 0);
        }
    }

#pragma unroll
    for (int j = 0; j < 8; ++j)
#pragma unroll
        for (int r = 0; r < 4; ++r)
            Ol[(w * 16 + q * 4 + r) * 132 + j * 16 + n] = acc[j][r];
    __syncthreads();

    const int row = tid >> 2;
    const int seg = tid & 3;
    const float* Lr = &Ol[row * 132 + seg * 32];
    float*       Or = out + ((size_t)b * SS + s0 + row) * OO + seg * 32;
#pragma unroll
    for (int c = 0; c < 8; ++c) {
        float4 v        = *(const float4*)(Lr + c * 4);
        const float4 bv = *(const float4*)(bias + seg * 32 + c * 4);
        v.x += bv.x; v.y += bv.y; v.z += bv.z; v.w += bv.w;
        *(float4*)(Or + c * 4) = v;
    }
}

extern "C" void kernel_launch(void* const* d_in, const int* in_sizes, int n_in,
                              void* d_out, int out_size, void* d_ws, size_t ws_size,
                              hipStream_t stream) {
    const float* X    = (const float*)d_in[0];  // [B,S,D]
    const float* W    = (const float*)d_in[1];  // [OUT,S]
    const float* bias = (const float*)d_in[2];  // [OUT]
    float* out = (float*)d_out;                 // [B,S,OUT]

    // ws layout (~25 MB; ws observed = 256 MiB)
    float*          Yp = (float*)d_ws;                          // [32][B][OO][DD] fp32
    unsigned short* XB = (unsigned short*)(Yp + (size_t)32 * YN);
    unsigned short* XT = XB + (size_t)BB * SS * DD;
    unsigned short* WB = XT + (size_t)BB * SS * DD;
    unsigned short* YB = WB + (size_t)OO * SS;

    k_prep<<<dim3(576), dim3(256), 0, stream>>>(X, W, XB, XT, WB);
    k_y2<32><<<dim3(512), dim3(256), 0, stream>>>(WB, XT, Yp);
    k_red<32><<<dim3(128), dim3(256), 0, stream>>>(Yp, YB);
    k_out2<<<dim3(512), dim3(256), 0, stream>>>(XB, YB, bias, out);
}

// Round 5
// 80.177 us; speedup vs baseline: 1.6482x; 1.1714x over previous
//
#include <hip/hip_runtime.h>

#define BB 16
#define SS 2048
#define DD 64
#define OO 128
#define SPL 16
#define YN (BB * OO * DD)   // 131072 Y elements

typedef __attribute__((ext_vector_type(8))) short short8;   // 8 bf16 = 4 VGPRs
typedef __attribute__((ext_vector_type(4))) float f32x4;

__device__ __forceinline__ unsigned short f2bf(float f) {   // RNE fp32->bf16
    unsigned int u = __float_as_uint(f);
    return (unsigned short)((u + 0x7FFF + ((u >> 16) & 1)) >> 16);
}
__device__ __forceinline__ unsigned int pk2(float x, float y) {
    return (unsigned int)f2bf(x) | ((unsigned int)f2bf(y) << 16);
}
__device__ __forceinline__ short8 cvt8(float4 a, float4 b) {
    uint4 u = make_uint4(pk2(a.x, a.y), pk2(a.z, a.w), pk2(b.x, b.y), pk2(b.z, b.w));
    return *(short8*)&u;
}

// ---------------------------------------------------------------------------
// k_yf: partial Y[p][b][o][d] = sum_{t in slice} W[o,t] * X[b,t,d]
// grid = 256 (b = bx&15, p = bx>>4), 512 thr (8 waves). K-slice = 128 t.
// Stage X slice transposed to bf16 in LDS: XT[d 0..63][t 0..127], stride 132
// (264B rows: ds b64 ops land ~4-way bank aliasing = near-free, m136).
// A-frags: W fp32 from global (L2-shared by 16 b-blocks), inline cvt.
// Wave w owns o-rows [w*16, w*16+16); j = d-tile 0..3; 16 MFMA/wave.
// ---------------------------------------------------------------------------
__global__ __launch_bounds__(512) void k_yf(const float* __restrict__ X,
                                            const float* __restrict__ W,
                                            float* __restrict__ Yp) {
    __shared__ unsigned short XT[64 * 132];

    const int bx  = blockIdx.x;
    const int b   = bx & 15;
    const int p   = bx >> 4;
    const int t0  = p * (SS / SPL);        // 128-wide t slice
    const int tid = threadIdx.x;
    const int w   = tid >> 6;
    const int l   = tid & 63;

    // ---- stage: lane l = d, coalesced 256B row loads, packed b64 LDS writes
    const float* Xb = X + ((size_t)b * SS + t0) * DD;
#pragma unroll
    for (int i = 0; i < 4; ++i) {
        const int tl = w * 4 + i * 32;     // 0..124, step 4 per wave
        float x0 = Xb[(size_t)(tl + 0) * DD + l];
        float x1 = Xb[(size_t)(tl + 1) * DD + l];
        float x2 = Xb[(size_t)(tl + 2) * DD + l];
        float x3 = Xb[(size_t)(tl + 3) * DD + l];
        uint2 h  = make_uint2(pk2(x0, x1), pk2(x2, x3));
        *(uint2*)&XT[l * 132 + tl] = h;    // 8B-aligned (264*l + 2*tl)
    }
    __syncthreads();

    const int n = l & 15;
    const int q = l >> 4;

    f32x4 acc[4];
#pragma unroll
    for (int j = 0; j < 4; ++j) acc[j] = {0.f, 0.f, 0.f, 0.f};

    const int orow = w * 16 + n;
    const float* Wr = W + (size_t)orow * SS + t0;

#pragma unroll
    for (int kk = 0; kk < SS / SPL; kk += 32) {
        const float4 wa = *(const float4*)(Wr + kk + q * 8);
        const float4 wb = *(const float4*)(Wr + kk + q * 8 + 4);
        const short8 a  = cvt8(wa, wb);
#pragma unroll
        for (int j = 0; j < 4; ++j) {
            const unsigned short* r = &XT[(j * 16 + n) * 132 + kk + q * 8];
            uint2 lo = *(const uint2*)(r);
            uint2 hi = *(const uint2*)(r + 4);
            uint4 u  = make_uint4(lo.x, lo.y, hi.x, hi.y);
            acc[j] = __builtin_amdgcn_mfma_f32_16x16x32_bf16(a, *(short8*)&u, acc[j], 0, 0, 0);
        }
    }

    float* Yb = Yp + ((size_t)(p * BB + b) * OO + w * 16 + q * 4) * DD;
#pragma unroll
    for (int j = 0; j < 4; ++j)
#pragma unroll
        for (int r = 0; r < 4; ++r)
            Yb[(size_t)r * DD + j * 16 + n] = acc[j][r];
}

// ---------------------------------------------------------------------------
// k_red: Y[n] (fp32) = sum_p Yp[p][n].  64 blocks x 512 thr, float4 each.
// ---------------------------------------------------------------------------
__global__ __launch_bounds__(512) void k_red(const float* __restrict__ Yp,
                                             float* __restrict__ Y) {
    const size_t i4 = ((size_t)blockIdx.x * 512 + threadIdx.x) * 4;
    float4 a = *(const float4*)(Yp + i4);
#pragma unroll
    for (int p = 1; p < SPL; ++p) {
        const float4 v = *(const float4*)(Yp + (size_t)p * YN + i4);
        a.x += v.x; a.y += v.y; a.z += v.z; a.w += v.w;
    }
    *(float4*)(Y + i4) = a;
}

// ---------------------------------------------------------------------------
// k_outf: out[b,s,o] = sum_d X[b,s,d]*Y[b,o,d] + bias[o]
// grid = 512 (b = bx>>5, s-tile 64), 256 thr (4 waves, 2 blocks/CU).
// YL: Y[b] as bf16 in LDS, 8-elem-chunk XOR swizzle c8^=(o&7) -> frag
// ds_read_b128 hits all 32 banks (conflict-free). A-frags inline-cvt from X.
// Direct global stores + bias (rows fully covered per wave -> L2 merges).
// ---------------------------------------------------------------------------
__global__ __launch_bounds__(256, 2) void k_outf(const float* __restrict__ X,
                                                 const float* __restrict__ Y,
                                                 const float* __restrict__ bias,
                                                 float* __restrict__ out) {
    __shared__ unsigned short YL[OO * DD];   // 16KB, swizzled

    const int bx  = blockIdx.x;
    const int b   = bx >> 5;
    const int s0  = (bx & 31) * 64;
    const int tid = threadIdx.x;
    const int w   = tid >> 6;
    const int l   = tid & 63;
    const int n   = l & 15;
    const int q   = l >> 4;

    // stage Y[b] -> bf16 LDS, swizzled: elem(o,c) = o*64 + ((c>>3 ^ (o&7))<<3) + (c&7)
    const float* Yb = Y + (size_t)b * OO * DD;
#pragma unroll
    for (int i = 0; i < 8; ++i) {
        const int f = (tid + 256 * i) * 4;   // 4 consecutive d
        const float4 v = *(const float4*)(Yb + f);
        const int o = f >> 6, c = f & 63;
        const int e = o * 64 + ((((c >> 3) ^ (o & 7)) << 3) | (c & 7));
        *(uint2*)&YL[e] = make_uint2(pk2(v.x, v.y), pk2(v.z, v.w));
    }

    float bv[8];
#pragma unroll
    for (int j = 0; j < 8; ++j) bv[j] = bias[j * 16 + n];

    f32x4 acc[8];
#pragma unroll
    for (int j = 0; j < 8; ++j) acc[j] = {0.f, 0.f, 0.f, 0.f};

    __syncthreads();

    const int srow = s0 + w * 16 + n;
    const float* Xr = X + ((size_t)b * SS + srow) * DD;

#pragma unroll
    for (int kk = 0; kk < DD; kk += 32) {
        const float4 xa = *(const float4*)(Xr + kk + q * 8);
        const float4 xb = *(const float4*)(Xr + kk + q * 8 + 4);
        const short8 a  = cvt8(xa, xb);
        const int c8    = (kk >> 3) + q;     // 8-elem chunk index of k
#pragma unroll
        for (int j = 0; j < 8; ++j) {
            const int o = j * 16 + n;
            const uint4 u = *(const uint4*)&YL[o * 64 + ((c8 ^ (o & 7)) << 3)];
            acc[j] = __builtin_amdgcn_mfma_f32_16x16x32_bf16(a, *(short8*)&u, acc[j], 0, 0, 0);
        }
    }

    float* op = out + ((size_t)b * SS + s0 + w * 16 + q * 4) * OO;
#pragma unroll
    for (int j = 0; j < 8; ++j)
#pragma unroll
        for (int r = 0; r < 4; ++r)
            op[(size_t)r * OO + j * 16 + n] = acc[j][r] + bv[j];
}

extern "C" void kernel_launch(void* const* d_in, const int* in_sizes, int n_in,
                              void* d_out, int out_size, void* d_ws, size_t ws_size,
                              hipStream_t stream) {
    const float* X    = (const float*)d_in[0];  // [B,S,D]
    const float* W    = (const float*)d_in[1];  // [OUT,S]
    const float* bias = (const float*)d_in[2];  // [OUT]
    float* out = (float*)d_out;                 // [B,S,OUT]

    float* Yp = (float*)d_ws;                   // [SPL][B][OO][DD] fp32, 8.4MB
    float* Y  = Yp + (size_t)SPL * YN;          // [B][OO][DD] fp32, 512KB

    k_yf <<<dim3(BB * SPL), dim3(512), 0, stream>>>(X, W, Yp);
    k_red<<<dim3(YN / 4 / 512), dim3(512), 0, stream>>>(Yp, Y);
    k_outf<<<dim3(512), dim3(256), 0, stream>>>(X, Y, bias, out);
}